// Round 6
// baseline (461.488 us; speedup 1.0000x reference)
//
#include <hip/hip_runtime.h>
#include <math.h>

#define NN 20000
#define NE 160000
#define NG 1000
#define IND 11
#define H 128
#define ED 3
#define NL 5
#define ZDH (259*128)
#define BN_EPSF 1e-5f
#define EPW 32    /* edges per wave in agg_edge (2x lane replication) */
#define GP 4      /* graphs per block in fused pool+mlp */
#define MBLK 313  /* ceil(NN/64) gemm row-blocks */

/* prep_fused block partition */
#define DEG_BLKS ((NE + 255) / 256)              /* 625  */
#define WPREP_BLKS ((NL * 512 * H + 255) / 256)  /* 1280 */
#define GB_BLKS ((NN + 255) / 256)               /* 79   */
#define HIN_BLKS 512
#define PREP_GRID (DEG_BLKS + WPREP_BLKS + GB_BLKS + HIN_BLKS)

typedef unsigned short ushort_t;
typedef unsigned int uint_t;
typedef __attribute__((ext_vector_type(8))) short bf8_t;
typedef __attribute__((ext_vector_type(4))) float f4_t;

__device__ inline ushort_t f2bf(float x) {
    unsigned int u = __float_as_uint(x);
    unsigned int r = (u + 0x7fffu + ((u >> 16) & 1u)) >> 16;
    return (ushort_t)r;
}
__device__ inline float bf2f(ushort_t b) {
    return __uint_as_float(((unsigned int)b) << 16);
}

// ---------------- fused prep: degree count + weight transpose + h_in GEMM
// + graph boundaries (batch is sorted). Partitioned by blockIdx.
// Wt layout: per layer, 4 tables (Pf,Ps,Qf,Qs); within a table, MFMA
// fragment order [nt][ks][lane][8 bf16] so the gemm loads B fragments as
// coalesced dwordx4 straight from L2 (no LDS staging).
__global__ __launch_bounds__(256) void prep_fused(const int* __restrict__ dst,
                                                  int* __restrict__ degi,
                                                  const float* __restrict__ Wf,
                                                  const float* __restrict__ Ws,
                                                  ushort_t* __restrict__ Wt,
                                                  const float* __restrict__ x,
                                                  const float* __restrict__ Win,
                                                  const float* __restrict__ bin,
                                                  float* __restrict__ h,
                                                  const int* __restrict__ batch,
                                                  int* __restrict__ gstart) {
    int b = blockIdx.x;
    int tid = threadIdx.x;
    if (b < DEG_BLKS) {
        int e = b * 256 + tid;
        if (e < NE) atomicAdd(&degi[dst[e]], 1);
    } else if (b < DEG_BLKS + WPREP_BLKS) {
        int idx = (b - DEG_BLKS) * 256 + tid;   // l*65536 + n*128 + k
        if (idx < NL * 512 * H) {
            int k = idx & 127;          // reduction index within table half
            int n = (idx >> 7) & 511;   // table*128 + output col j
            int l = idx >> 16;
            int t = n >> 7, j = n & 127;
            const float* W = (t == 0 || t == 2) ? Wf : Ws;
            int krow = (t < 2) ? k : (H + k);
            ushort_t val = f2bf(W[(size_t)l * ZDH + krow * H + j]);
            // fragment-order destination
            int nt = j >> 4, sub = j & 15;
            int ks = k >> 5, quad = (k >> 3) & 3, e2 = k & 7;
            int lane = quad * 16 + sub;
            Wt[(size_t)l * 65536 + (size_t)t * 16384 +
               (((nt * 4 + ks) * 64 + lane) * 8 + e2)] = val;
        }
    } else if (b < DEG_BLKS + WPREP_BLKS + GB_BLKS) {
        int n = (b - DEG_BLKS - WPREP_BLKS) * 256 + tid;
        if (n < NN) {
            int b0 = batch[n];
            int bn = (n + 1 < NN) ? batch[n + 1] : NG;
            if (n == 0)
                for (int t = 0; t <= b0; ++t) gstart[t] = 0;
            for (int t = b0 + 1; t <= bn; ++t) gstart[t] = n + 1;
        }
    } else {
        __shared__ float lw[IND * H];
        for (int i = tid; i < IND * H; i += 256) lw[i] = Win[i];
        __syncthreads();
        int j = tid & 127;
        float bj = bin[j];
        int rb = b - (DEG_BLKS + WPREP_BLKS + GB_BLKS);
        for (int n = rb * 2 + (tid >> 7); n < NN; n += HIN_BLKS * 2) {
            const float* xr = x + (size_t)n * IND;
            float acc = bj;
#pragma unroll
            for (int k = 0; k < IND; ++k) acc = fmaf(xr[k], lw[k * H + j], acc);
            h[(size_t)n * H + j] = acc;
        }
    }
}

// Prefix-scan CSR row starts; also writes the segment-end bitmask directly
// (end of node n's segment = cursor[n]+deg[n]-1) — replaces flag_kernel,
// which needed the scattered csr_dst and a full extra dispatch.
__global__ __launch_bounds__(256) void reserve_kernel(const int* __restrict__ degi,
                                                      int* __restrict__ cursor,
                                                      float* __restrict__ invdeg,
                                                      int* __restrict__ counter,
                                                      unsigned* __restrict__ endmask) {
    int n = blockIdx.x * blockDim.x + threadIdx.x;
    int lane = threadIdx.x & 63;
    int v = (n < NN) ? degi[n] : 0;
    int x = v;
#pragma unroll
    for (int st = 1; st < 64; st <<= 1) {
        int y = __shfl_up(x, st, 64);
        if (lane >= st) x += y;
    }
    int total = __shfl(x, 63, 64);
    int base = 0;
    if (lane == 63) base = atomicAdd(counter, total);
    base = __shfl(base, 63, 64);
    if (n < NN) {
        int st0 = base + x - v;
        cursor[n] = st0;
        invdeg[n] = 1.0f / (float)(v < 1 ? 1 : v);
        if (v > 0) {
            int endp = st0 + v - 1;
            atomicOr(&endmask[endp >> 5], 1u << (endp & 31));
        }
    }
}

__global__ void scatter_kernel(const int* __restrict__ src, const int* __restrict__ dst,
                               const float* __restrict__ ea,
                               const float* __restrict__ invdeg,
                               int* __restrict__ cursor, float4* __restrict__ csr_ea4,
                               int* __restrict__ csr_dst, float* __restrict__ csr_inv) {
    int e = blockIdx.x * blockDim.x + threadIdx.x;
    if (e < NE) {
        int d = dst[e];
        int pos = atomicAdd(&cursor[d], 1);
        float4 r;
        r.x = ea[e * ED + 0];
        r.y = ea[e * ED + 1];
        r.z = ea[e * ED + 2];
        r.w = __int_as_float(src[e]);
        csr_ea4[pos] = r;
        csr_dst[pos] = d;
        csr_inv[pos] = invdeg[d];
    }
}

// MFMA node GEMM v8: LDS-free. B fragments pre-swizzled into MFMA fragment
// order (coalesced dwordx4 from L2). BN scale/shift computed once per block.
__global__ __launch_bounds__(256, 4) void node_gemm_mfma(const float* __restrict__ hsrc,
                                                         float* __restrict__ hbn,
                                                         const ushort_t* __restrict__ Wt_l,
                                                         const float* __restrict__ sum,
                                                         const float* __restrict__ sumsq,
                                                         const float* __restrict__ gamma_l,
                                                         const float* __restrict__ beta_l,
                                                         int applyBN,
                                                         uint_t* __restrict__ ppack,
                                                         uint_t* __restrict__ qpack) {
    int pair = blockIdx.y;           // 0 -> (Pf,Ps), 1 -> (Qf,Qs)
    int tid = threadIdx.x;
    int wave = tid >> 6;
    int lane = tid & 63;
    int sub = lane & 15;
    int quad = lane >> 4;
    int m0 = blockIdx.x * 64 + wave * 16;
    int writeH = applyBN && (pair == 0);

    __shared__ float bnsc[H];
    __shared__ float bnsh[H];
    if (applyBN) {
        if (tid < H) {
            float mu  = sum[tid] * (1.0f / NN);
            float var = sumsq[tid] * (1.0f / NN) - mu * mu;
            float sc  = gamma_l[tid] * rsqrtf(var + BN_EPSF);
            bnsc[tid] = sc;
            bnsh[tid] = beta_l[tid] - mu * sc;
        }
        __syncthreads();
    }

    const bf8_t* fragF = (const bf8_t*)(Wt_l + (size_t)(2 * pair) * 16384);
    const bf8_t* fragS = (const bf8_t*)(Wt_l + (size_t)(2 * pair + 1) * 16384);

    // ---- A staging: fp32 h -> optional BN+ReLU -> bf16 hi/lo ----
    bf8_t aHi[4], aLo[4];
    int r = m0 + sub;
    int rc = r < NN ? r : NN - 1;
#pragma unroll
    for (int ks = 0; ks < 4; ++ks) {
        int kb = ks * 32 + quad * 8;
        const float* hp = hsrc + (size_t)rc * H + kb;
        float4 v0 = *(const float4*)hp;
        float4 v1 = *(const float4*)(hp + 4);
        float vv[8] = {v0.x, v0.y, v0.z, v0.w, v1.x, v1.y, v1.z, v1.w};
        if (applyBN) {
#pragma unroll
            for (int i = 0; i < 8; ++i) {
                float v = fmaf(vv[i], bnsc[kb + i], bnsh[kb + i]);
                vv[i] = v > 0.0f ? v : 0.0f;
            }
        }
        bf8_t hi8, lo8;
#pragma unroll
        for (int i = 0; i < 8; ++i) {
            ushort_t hi = f2bf(vv[i]);
            hi8[i] = (short)hi;
            lo8[i] = (short)f2bf(vv[i] - bf2f(hi));
        }
        aHi[ks] = hi8;
        aLo[ks] = lo8;
        if (writeH && r < NN) {
            float* op = hbn + (size_t)r * H + kb;
            *(float4*)op = make_float4(vv[0], vv[1], vv[2], vv[3]);
            *(float4*)(op + 4) = make_float4(vv[4], vv[5], vv[6], vv[7]);
        }
    }

    f4_t accF[8], accS[8];
#pragma unroll
    for (int b = 0; b < 8; ++b) { accF[b] = (f4_t){0.f, 0.f, 0.f, 0.f}; accS[b] = (f4_t){0.f, 0.f, 0.f, 0.f}; }

#pragma unroll
    for (int nt = 0; nt < 8; ++nt) {
#pragma unroll
        for (int ks = 0; ks < 4; ++ks) {
            bf8_t bF = fragF[(nt * 4 + ks) * 64 + lane];
            bf8_t bS = fragS[(nt * 4 + ks) * 64 + lane];
            accF[nt] = __builtin_amdgcn_mfma_f32_16x16x32_bf16(aHi[ks], bF, accF[nt], 0, 0, 0);
            accF[nt] = __builtin_amdgcn_mfma_f32_16x16x32_bf16(aLo[ks], bF, accF[nt], 0, 0, 0);
            accS[nt] = __builtin_amdgcn_mfma_f32_16x16x32_bf16(aHi[ks], bS, accS[nt], 0, 0, 0);
            accS[nt] = __builtin_amdgcn_mfma_f32_16x16x32_bf16(aLo[ks], bS, accS[nt], 0, 0, 0);
        }
    }

    uint_t* outp = pair ? qpack : ppack;
#pragma unroll
    for (int nt = 0; nt < 8; ++nt) {
        int col = nt * 16 + sub;
#pragma unroll
        for (int rr = 0; rr < 4; ++rr) {
            int row = m0 + quad * 4 + rr;
            if (row < NN) {
                uint_t lo = f2bf(accF[nt][rr]);
                uint_t hi = f2bf(accS[nt][rr]);
                outp[(size_t)row * H + col] = lo | (hi << 16);
            }
        }
    }
}

// Edge-parallel segmented CSR aggregation, EPW=32 with a FULL-window
// q-prefetch: all 32 gathers issued back-to-back in the prologue (max
// memory-level parallelism for the L3-latency-bound phase), no inner-loop
// refill. Bias folded into P at segment load ((pf+bias)+qf keeps the exact
// FP association of the previous version -> bit-identical results).
__global__ __launch_bounds__(256) void agg_edge_kernel(const int4* __restrict__ csr_fe,
                                                       const int* __restrict__ csr_dst,
                                                       const float* __restrict__ csr_inv,
                                                       const unsigned* __restrict__ endmask,
                                                       const float* __restrict__ Wf,
                                                       const float* __restrict__ bf,
                                                       const float* __restrict__ Ws,
                                                       const float* __restrict__ bs,
                                                       const uint_t* __restrict__ ppack,
                                                       const uint_t* __restrict__ qpack,
                                                       float* __restrict__ h,
                                                       float* __restrict__ sum,
                                                       float* __restrict__ sumsq) {
    int tid = threadIdx.x;
    if (blockIdx.x == 0 && tid < H) { sum[tid] = 0.0f; sumsq[tid] = 0.0f; }
    int lane = tid & 63;
    int wv = tid >> 6;
    int base = (blockIdx.x * 4 + wv) * EPW;
    int c0 = 2 * lane;

    float2 wf0 = *(const float2*)&Wf[256 * H + c0];
    float2 wf1 = *(const float2*)&Wf[257 * H + c0];
    float2 wf2 = *(const float2*)&Wf[258 * H + c0];
    float2 ws0 = *(const float2*)&Ws[256 * H + c0];
    float2 ws1 = *(const float2*)&Ws[257 * H + c0];
    float2 ws2 = *(const float2*)&Ws[258 * H + c0];
    float2 bf2_ = *(const float2*)&bf[c0];
    float2 bs2_ = *(const float2*)&bs[c0];

    // lanes replicate 32 edge records 2x (broadcast reads)
    int4 fe = csr_fe[base + (lane & (EPW - 1))];
    int  dd = csr_dst[base + (lane & (EPW - 1))];
    int  ivr = __float_as_int(csr_inv[base + (lane & (EPW - 1))]);
    // base is a multiple of 32 -> the endmask word is exactly this window
    unsigned mask = __builtin_amdgcn_readfirstlane(endmask[base >> 5]);

    uint2 q[EPW];
#pragma unroll
    for (int i = 0; i < EPW; ++i) {
        int s = __builtin_amdgcn_readlane(fe.w, i);
        q[i] = *(const uint2*)&qpack[(size_t)s * H + c0];
    }

    int dcur = __builtin_amdgcn_readlane(dd, 0);
    uint2 ppc = *(const uint2*)&ppack[(size_t)dcur * H + c0];
    float pf0 = __uint_as_float(ppc.x << 16) + bf2_.x;
    float ps0 = __uint_as_float(ppc.x & 0xFFFF0000u) + bs2_.x;
    float pf1 = __uint_as_float(ppc.y << 16) + bf2_.y;
    float ps1 = __uint_as_float(ppc.y & 0xFFFF0000u) + bs2_.y;
    unsigned m = mask;
    int e0 = m ? __builtin_ctz(m) : EPW;
    int dnext = 0;
    uint2 ppN = ppc;
    if (e0 + 1 < EPW) {
        dnext = __builtin_amdgcn_readlane(dd, e0 + 1);
        ppN = *(const uint2*)&ppack[(size_t)dnext * H + c0];
    }

    float acc0 = 0.f, acc1 = 0.f;

#pragma unroll
    for (int tb = 0; tb < EPW; tb += 8) {
#pragma unroll
        for (int i = 0; i < 8; ++i) {
            int t = tb + i;
            float ex = __int_as_float(__builtin_amdgcn_readlane(fe.x, t));
            float ey = __int_as_float(__builtin_amdgcn_readlane(fe.y, t));
            float ez = __int_as_float(__builtin_amdgcn_readlane(fe.z, t));
            uint2 qq = q[t];
            float qf0 = __uint_as_float(qq.x << 16);
            float qs0 = __uint_as_float(qq.x & 0xFFFF0000u);
            float qf1 = __uint_as_float(qq.y << 16);
            float qs1 = __uint_as_float(qq.y & 0xFFFF0000u);
            float f0 = fmaf(ex, wf0.x, fmaf(ey, wf1.x, fmaf(ez, wf2.x, pf0 + qf0)));
            float v0 = fmaf(ex, ws0.x, fmaf(ey, ws1.x, fmaf(ez, ws2.x, ps0 + qs0)));
            float f1 = fmaf(ex, wf0.y, fmaf(ey, wf1.y, fmaf(ez, wf2.y, pf1 + qf1)));
            float v1 = fmaf(ex, ws0.y, fmaf(ey, ws1.y, fmaf(ez, ws2.y, ps1 + qs1)));
            float sig0 = __builtin_amdgcn_rcpf(1.0f + __expf(-f0));
            float sp0  = fmaxf(v0, 0.0f) + __logf(1.0f + __expf(-fabsf(v0)));
            float sig1 = __builtin_amdgcn_rcpf(1.0f + __expf(-f1));
            float sp1  = fmaxf(v1, 0.0f) + __logf(1.0f + __expf(-fabsf(v1)));
            acc0 = fmaf(sig0, sp0, acc0);
            acc1 = fmaf(sig1, sp1, acc1);
            if (mask & (1u << t)) {   // wave-uniform segment end (precomputed)
                float inv = __int_as_float(__builtin_amdgcn_readlane(ivr, t));
                atomicAdd(&h[(size_t)dcur * H + c0], acc0 * inv);
                atomicAdd(&h[(size_t)dcur * H + c0 + 1], acc1 * inv);
                acc0 = 0.f; acc1 = 0.f;
                dcur = dnext;
                pf0 = __uint_as_float(ppN.x << 16) + bf2_.x;
                ps0 = __uint_as_float(ppN.x & 0xFFFF0000u) + bs2_.x;
                pf1 = __uint_as_float(ppN.y << 16) + bf2_.y;
                ps1 = __uint_as_float(ppN.y & 0xFFFF0000u) + bs2_.y;
                m &= m - 1;
                int e1 = m ? __builtin_ctz(m) : EPW;
                if (e1 + 1 < EPW) {
                    dnext = __builtin_amdgcn_readlane(dd, e1 + 1);
                    ppN = *(const uint2*)&ppack[(size_t)dnext * H + c0];
                }
            }
        }
    }
    if (!(mask & (1u << (EPW - 1)))) {   // trailing partial segment
        float inv = __int_as_float(__builtin_amdgcn_readlane(ivr, EPW - 1));
        atomicAdd(&h[(size_t)dcur * H + c0], acc0 * inv);
        atomicAdd(&h[(size_t)dcur * H + c0 + 1], acc1 * inv);
    }
}

// per-column sum / sumsq; 8 independent row loads per iteration.
__global__ __launch_bounds__(H) void stats_kernel(const float* __restrict__ h,
                                                  float* __restrict__ sum,
                                                  float* __restrict__ sumsq) {
    int j = threadIdx.x;
    float s = 0.0f, ss = 0.0f;
    int n = blockIdx.x * 8;
    for (; n + 7 < NN; n += gridDim.x * 8) {
        float v[8];
#pragma unroll
        for (int i = 0; i < 8; ++i) v[i] = h[(size_t)(n + i) * H + j];
#pragma unroll
        for (int i = 0; i < 8; ++i) { s += v[i]; ss = fmaf(v[i], v[i], ss); }
    }
    for (; n < NN; ++n) {
        float v = h[(size_t)n * H + j];
        s += v;
        ss = fmaf(v, v, ss);
    }
    atomicAdd(&sum[j], s);
    atomicAdd(&sumsq[j], ss);
}

// Fused global-mean-pool (atomic-free, batch sorted -> contiguous ranges)
// + BN/ReLU epilogue + 3-layer MLP. GP graphs per block for weight reuse.
__global__ __launch_bounds__(H) void pool_mlp_kernel(const float* __restrict__ h,
                                                     const int* __restrict__ gstart,
                                                     const float* __restrict__ sum,
                                                     const float* __restrict__ sumsq,
                                                     const float* __restrict__ gamma,
                                                     const float* __restrict__ beta,
                                                     const float* __restrict__ W1,
                                                     const float* __restrict__ b1,
                                                     const float* __restrict__ W2,
                                                     const float* __restrict__ b2,
                                                     const float* __restrict__ W3,
                                                     const float* __restrict__ b3,
                                                     float* __restrict__ out) {
    int j = threadIdx.x;
    float mu  = sum[j] * (1.0f / NN);
    float var = sumsq[j] * (1.0f / NN) - mu * mu;
    float sc  = gamma[j] * rsqrtf(var + BN_EPSF);
    float sh  = beta[j] - mu * sc;

    __shared__ float s1[GP][H];
    __shared__ float s2[GP][H];

#pragma unroll
    for (int gi = 0; gi < GP; ++gi) {
        int g0 = blockIdx.x * GP + gi;
        int a = gstart[g0], e = gstart[g0 + 1];
        float p0 = 0.f, p1 = 0.f, p2 = 0.f, p3 = 0.f;
        int n = a;
        for (; n + 3 < e; n += 4) {
            float v0 = fmaf(h[(size_t)(n + 0) * H + j], sc, sh);
            float v1 = fmaf(h[(size_t)(n + 1) * H + j], sc, sh);
            float v2 = fmaf(h[(size_t)(n + 2) * H + j], sc, sh);
            float v3 = fmaf(h[(size_t)(n + 3) * H + j], sc, sh);
            p0 += fmaxf(v0, 0.f); p1 += fmaxf(v1, 0.f);
            p2 += fmaxf(v2, 0.f); p3 += fmaxf(v3, 0.f);
        }
        for (; n < e; ++n) {
            float v = fmaf(h[(size_t)n * H + j], sc, sh);
            p0 += fmaxf(v, 0.f);
        }
        float cf = (float)(e - a);
        if (cf < 1.f) cf = 1.f;
        s1[gi][j] = ((p0 + p1) + (p2 + p3)) / cf;
    }
    __syncthreads();

    float a1[GP];
#pragma unroll
    for (int gi = 0; gi < GP; ++gi) a1[gi] = b1[j];
    for (int k = 0; k < H; ++k) {
        float w = W1[k * H + j];
#pragma unroll
        for (int gi = 0; gi < GP; ++gi) a1[gi] = fmaf(s1[gi][k], w, a1[gi]);
    }
#pragma unroll
    for (int gi = 0; gi < GP; ++gi) s2[gi][j] = fmaxf(a1[gi], 0.f);
    __syncthreads();

#pragma unroll
    for (int gi = 0; gi < GP; ++gi) a1[gi] = b2[j];
    for (int k = 0; k < H; ++k) {
        float w = W2[k * H + j];
#pragma unroll
        for (int gi = 0; gi < GP; ++gi) a1[gi] = fmaf(s2[gi][k], w, a1[gi]);
    }

    float w3 = W3[j];
    __shared__ float wred[2][GP];
#pragma unroll
    for (int gi = 0; gi < GP; ++gi) {
        float p = fmaxf(a1[gi], 0.f) * w3;
        for (int off2 = 32; off2 > 0; off2 >>= 1) p += __shfl_down(p, off2, 64);
        if ((j & 63) == 0) wred[j >> 6][gi] = p;
    }
    __syncthreads();
    if (j < GP) out[blockIdx.x * GP + j] = wred[0][j] + wred[1][j] + b3[0];
}

extern "C" void kernel_launch(void* const* d_in, const int* in_sizes, int n_in,
                              void* d_out, int out_size, void* d_ws, size_t ws_size,
                              hipStream_t stream) {
    const float* x     = (const float*)d_in[0];
    const int*   ei    = (const int*)d_in[1];
    const int*   srcp  = ei;        // edge_index[0] = source (x_j)
    const int*   dstp  = ei + NE;   // edge_index[1] = target (aggregation index)
    const int*   batch = (const int*)d_in[2];
    const float* ea    = (const float*)d_in[3];
    const float* Win   = (const float*)d_in[4];
    const float* bin   = (const float*)d_in[5];
    const float* Wf    = (const float*)d_in[6];
    const float* bf    = (const float*)d_in[7];
    const float* Ws    = (const float*)d_in[8];
    const float* bs    = (const float*)d_in[9];
    const float* gamma = (const float*)d_in[10];
    const float* beta  = (const float*)d_in[11];
    const float* W1    = (const float*)d_in[12];
    const float* b1    = (const float*)d_in[13];
    const float* W2    = (const float*)d_in[14];
    const float* b2    = (const float*)d_in[15];
    const float* W3    = (const float*)d_in[16];
    const float* b3    = (const float*)d_in[17];
    float* out = (float*)d_out;

    const size_t NH = (size_t)NN * H;
    float* wsp = (float*)d_ws;
    size_t off = 0;
    float* hA     = wsp + off; off += NH;
    float* hB     = wsp + off; off += NH;
    uint_t* ppack = (uint_t*)(wsp + off); off += NH;  // packed bf16 (Pf,Ps)
    uint_t* qpack = (uint_t*)(wsp + off); off += NH;  // packed bf16 (Qf,Qs)
    float* invdeg = wsp + off; off += NN;
    float* sum    = wsp + off; off += H;
    float* sumsq  = wsp + off; off += H;
    int* gstart   = (int*)(wsp + off); off += NG + 1;
    off = (off + 3) & ~(size_t)3;
    float4* csr_ea4 = (float4*)(wsp + off); off += (size_t)NE * 4;
    float* csr_inv = wsp + off; off += NE;
    int* degi      = (int*)(wsp + off); off += NN;
    int* counter   = (int*)(wsp + off); off += 1;
    unsigned* endmask = (unsigned*)(wsp + off); off += NE / 32;
    int* cursor    = (int*)(wsp + off); off += NN;
    int* csr_dst   = (int*)(wsp + off); off += NE;
    off = (off + 3) & ~(size_t)3;
    ushort_t* Wt = (ushort_t*)(wsp + off); off += (size_t)NL * 512 * H / 2;

    // ---- CSR + weight prep (topology/weights fixed across layers) ----
    // zero degi + counter + endmask in one memset (contiguous)
    hipMemsetAsync(degi, 0, (NN + 1 + NE / 32) * sizeof(int), stream);
    prep_fused<<<PREP_GRID, 256, 0, stream>>>(dstp, degi, Wf, Ws, Wt,
                                              x, Win, bin, hA, batch, gstart);
    reserve_kernel<<<(NN + 255) / 256, 256, 0, stream>>>(degi, cursor, invdeg, counter,
                                                         endmask);
    scatter_kernel<<<(NE + 255) / 256, 256, 0, stream>>>(srcp, dstp, ea, invdeg, cursor,
                                                         csr_ea4, csr_dst, csr_inv);

    float* hRead = hA;
    for (int l = 0; l < NL; ++l) {
        float* hTgt = (l == 0) ? hA : ((l & 1) ? hB : hA);
        node_gemm_mfma<<<dim3(MBLK, 2), 256, 0, stream>>>(
            hRead, hTgt,
            Wt + (size_t)l * 512 * H,
            sum, sumsq,
            gamma + (size_t)(l ? l - 1 : 0) * H,
            beta  + (size_t)(l ? l - 1 : 0) * H,
            l > 0, ppack, qpack);
        agg_edge_kernel<<<NE / (4 * EPW), 256, 0, stream>>>((const int4*)csr_ea4, csr_dst,
                                                            csr_inv, endmask,
                                                            Wf + (size_t)l * ZDH, bf + (size_t)l * H,
                                                            Ws + (size_t)l * ZDH, bs + (size_t)l * H,
                                                            ppack, qpack,
                                                            hTgt, sum, sumsq);
        stats_kernel<<<512, H, 0, stream>>>(hTgt, sum, sumsq);
        hRead = hTgt;
    }

    pool_mlp_kernel<<<NG / GP, H, 0, stream>>>(hRead, gstart, sum, sumsq,
                                               gamma + (size_t)(NL - 1) * H,
                                               beta + (size_t)(NL - 1) * H,
                                               W1, b1, W2, b2, W3, b3, out);
}

// Round 7
// 453.614 us; speedup vs baseline: 1.0174x; 1.0174x over previous
//
#include <hip/hip_runtime.h>
#include <hip/hip_cooperative_groups.h>
#include <math.h>

namespace cg = cooperative_groups;

#define NN 20000
#define NE 160000
#define NG 1000
#define IND 11
#define H 128
#define ED 3
#define NL 5
#define ZDH (259*128)
#define BN_EPSF 1e-5f
#define EPW 32    /* edges per wave in agg (2x lane replication) */
#define QR 16     /* q-prefetch ring depth (32 VGPR; deeper hurt occupancy, R6) */
#define GP 4      /* graphs per block in fused pool+mlp */
#define MBLK 313  /* ceil(NN/64) gemm row-blocks */
#define NWIN (NE / EPW)   /* 5000 aggregation windows */
#define MEGA_BLOCKS 1024  /* 4 blocks/CU x 256 CUs, co-residency verified */

/* prep_fused block partition */
#define DEG_BLKS ((NE + 255) / 256)              /* 625  */
#define WPREP_BLKS ((NL * 512 * H + 255) / 256)  /* 1280 */
#define GB_BLKS ((NN + 255) / 256)               /* 79   */
#define HIN_BLKS 512
#define PREP_GRID (DEG_BLKS + WPREP_BLKS + GB_BLKS + HIN_BLKS)

typedef unsigned short ushort_t;
typedef unsigned int uint_t;
typedef __attribute__((ext_vector_type(8))) short bf8_t;
typedef __attribute__((ext_vector_type(4))) float f4_t;

__device__ inline ushort_t f2bf(float x) {
    unsigned int u = __float_as_uint(x);
    unsigned int r = (u + 0x7fffu + ((u >> 16) & 1u)) >> 16;
    return (ushort_t)r;
}
__device__ inline float bf2f(ushort_t b) {
    return __uint_as_float(((unsigned int)b) << 16);
}

// ---------------- fused prep: degree count + weight transpose + h_in GEMM
// + graph boundaries (batch is sorted). Partitioned by blockIdx.
// Wt layout: per layer, 4 tables (Pf,Ps,Qf,Qs) in MFMA fragment order
// [nt][ks][lane][8 bf16] -> gemm loads B fragments as coalesced dwordx4.
__global__ __launch_bounds__(256) void prep_fused(const int* __restrict__ dst,
                                                  int* __restrict__ degi,
                                                  const float* __restrict__ Wf,
                                                  const float* __restrict__ Ws,
                                                  ushort_t* __restrict__ Wt,
                                                  const float* __restrict__ x,
                                                  const float* __restrict__ Win,
                                                  const float* __restrict__ bin,
                                                  float* __restrict__ h,
                                                  const int* __restrict__ batch,
                                                  int* __restrict__ gstart) {
    int b = blockIdx.x;
    int tid = threadIdx.x;
    if (b < DEG_BLKS) {
        int e = b * 256 + tid;
        if (e < NE) atomicAdd(&degi[dst[e]], 1);
    } else if (b < DEG_BLKS + WPREP_BLKS) {
        int idx = (b - DEG_BLKS) * 256 + tid;   // l*65536 + n*128 + k
        if (idx < NL * 512 * H) {
            int k = idx & 127;
            int n = (idx >> 7) & 511;
            int l = idx >> 16;
            int t = n >> 7, j = n & 127;
            const float* W = (t == 0 || t == 2) ? Wf : Ws;
            int krow = (t < 2) ? k : (H + k);
            ushort_t val = f2bf(W[(size_t)l * ZDH + krow * H + j]);
            int nt = j >> 4, sub = j & 15;
            int ks = k >> 5, quad = (k >> 3) & 3, e2 = k & 7;
            int lane = quad * 16 + sub;
            Wt[(size_t)l * 65536 + (size_t)t * 16384 +
               (((nt * 4 + ks) * 64 + lane) * 8 + e2)] = val;
        }
    } else if (b < DEG_BLKS + WPREP_BLKS + GB_BLKS) {
        int n = (b - DEG_BLKS - WPREP_BLKS) * 256 + tid;
        if (n < NN) {
            int b0 = batch[n];
            int bn = (n + 1 < NN) ? batch[n + 1] : NG;
            if (n == 0)
                for (int t = 0; t <= b0; ++t) gstart[t] = 0;
            for (int t = b0 + 1; t <= bn; ++t) gstart[t] = n + 1;
        }
    } else {
        __shared__ float lw[IND * H];
        for (int i = tid; i < IND * H; i += 256) lw[i] = Win[i];
        __syncthreads();
        int j = tid & 127;
        float bj = bin[j];
        int rb = b - (DEG_BLKS + WPREP_BLKS + GB_BLKS);
        for (int n = rb * 2 + (tid >> 7); n < NN; n += HIN_BLKS * 2) {
            const float* xr = x + (size_t)n * IND;
            float acc = bj;
#pragma unroll
            for (int k = 0; k < IND; ++k) acc = fmaf(xr[k], lw[k * H + j], acc);
            h[(size_t)n * H + j] = acc;
        }
    }
}

// Prefix-scan CSR row starts; writes the segment-end bitmask directly
// (end of node n's segment = start + deg - 1) — no flag_kernel dispatch.
__global__ __launch_bounds__(256) void reserve_kernel(const int* __restrict__ degi,
                                                      int* __restrict__ cursor,
                                                      float* __restrict__ invdeg,
                                                      int* __restrict__ counter,
                                                      unsigned* __restrict__ endmask) {
    int n = blockIdx.x * blockDim.x + threadIdx.x;
    int lane = threadIdx.x & 63;
    int v = (n < NN) ? degi[n] : 0;
    int x = v;
#pragma unroll
    for (int st = 1; st < 64; st <<= 1) {
        int y = __shfl_up(x, st, 64);
        if (lane >= st) x += y;
    }
    int total = __shfl(x, 63, 64);
    int base = 0;
    if (lane == 63) base = atomicAdd(counter, total);
    base = __shfl(base, 63, 64);
    if (n < NN) {
        int st0 = base + x - v;
        cursor[n] = st0;
        invdeg[n] = 1.0f / (float)(v < 1 ? 1 : v);
        if (v > 0) {
            int endp = st0 + v - 1;
            atomicOr(&endmask[endp >> 5], 1u << (endp & 31));
        }
    }
}

__global__ void scatter_kernel(const int* __restrict__ src, const int* __restrict__ dst,
                               const float* __restrict__ ea,
                               const float* __restrict__ invdeg,
                               int* __restrict__ cursor, float4* __restrict__ csr_ea4,
                               int* __restrict__ csr_dst, float* __restrict__ csr_inv) {
    int e = blockIdx.x * blockDim.x + threadIdx.x;
    if (e < NE) {
        int d = dst[e];
        int pos = atomicAdd(&cursor[d], 1);
        float4 r;
        r.x = ea[e * ED + 0];
        r.y = ea[e * ED + 1];
        r.z = ea[e * ED + 2];
        r.w = __int_as_float(src[e]);
        csr_ea4[pos] = r;
        csr_dst[pos] = d;
        csr_inv[pos] = invdeg[d];
    }
}

// ================= phase bodies (shared by mega and fallback) ===============

// One gemm item: 64 rows x one table pair. LDS-free (R4); BN consts passed in.
__device__ __forceinline__ void gemm_item(int mb, int pair,
                                          const float* __restrict__ hsrc,
                                          float* __restrict__ hbn,
                                          const ushort_t* __restrict__ Wt_l,
                                          const float* bnsc, const float* bnsh,
                                          int applyBN,
                                          uint_t* __restrict__ ppack,
                                          uint_t* __restrict__ qpack, int tid) {
    int wave = tid >> 6;
    int lane = tid & 63;
    int sub = lane & 15;
    int quad = lane >> 4;
    int m0 = mb * 64 + wave * 16;
    int writeH = applyBN && (pair == 0);

    const bf8_t* fragF = (const bf8_t*)(Wt_l + (size_t)(2 * pair) * 16384);
    const bf8_t* fragS = (const bf8_t*)(Wt_l + (size_t)(2 * pair + 1) * 16384);

    bf8_t aHi[4], aLo[4];
    int r = m0 + sub;
    int rc = r < NN ? r : NN - 1;
#pragma unroll
    for (int ks = 0; ks < 4; ++ks) {
        int kb = ks * 32 + quad * 8;
        const float* hp = hsrc + (size_t)rc * H + kb;
        float4 v0 = *(const float4*)hp;
        float4 v1 = *(const float4*)(hp + 4);
        float vv[8] = {v0.x, v0.y, v0.z, v0.w, v1.x, v1.y, v1.z, v1.w};
        if (applyBN) {
#pragma unroll
            for (int i = 0; i < 8; ++i) {
                float v = fmaf(vv[i], bnsc[kb + i], bnsh[kb + i]);
                vv[i] = v > 0.0f ? v : 0.0f;
            }
        }
        bf8_t hi8, lo8;
#pragma unroll
        for (int i = 0; i < 8; ++i) {
            ushort_t hi = f2bf(vv[i]);
            hi8[i] = (short)hi;
            lo8[i] = (short)f2bf(vv[i] - bf2f(hi));
        }
        aHi[ks] = hi8;
        aLo[ks] = lo8;
        if (writeH && r < NN) {
            float* op = hbn + (size_t)r * H + kb;
            *(float4*)op = make_float4(vv[0], vv[1], vv[2], vv[3]);
            *(float4*)(op + 4) = make_float4(vv[4], vv[5], vv[6], vv[7]);
        }
    }

    f4_t accF[8], accS[8];
#pragma unroll
    for (int b = 0; b < 8; ++b) { accF[b] = (f4_t){0.f, 0.f, 0.f, 0.f}; accS[b] = (f4_t){0.f, 0.f, 0.f, 0.f}; }

#pragma unroll
    for (int nt = 0; nt < 8; ++nt) {
#pragma unroll
        for (int ks = 0; ks < 4; ++ks) {
            bf8_t bF = fragF[(nt * 4 + ks) * 64 + lane];
            bf8_t bS = fragS[(nt * 4 + ks) * 64 + lane];
            accF[nt] = __builtin_amdgcn_mfma_f32_16x16x32_bf16(aHi[ks], bF, accF[nt], 0, 0, 0);
            accF[nt] = __builtin_amdgcn_mfma_f32_16x16x32_bf16(aLo[ks], bF, accF[nt], 0, 0, 0);
            accS[nt] = __builtin_amdgcn_mfma_f32_16x16x32_bf16(aHi[ks], bS, accS[nt], 0, 0, 0);
            accS[nt] = __builtin_amdgcn_mfma_f32_16x16x32_bf16(aLo[ks], bS, accS[nt], 0, 0, 0);
        }
    }

    uint_t* outp = pair ? qpack : ppack;
#pragma unroll
    for (int nt = 0; nt < 8; ++nt) {
        int col = nt * 16 + sub;
#pragma unroll
        for (int rr = 0; rr < 4; ++rr) {
            int row = m0 + quad * 4 + rr;
            if (row < NN) {
                uint_t lo = f2bf(accF[nt][rr]);
                uint_t hi = f2bf(accS[nt][rr]);
                outp[(size_t)row * H + col] = lo | (hi << 16);
            }
        }
    }
}

struct AggW { float2 wf0, wf1, wf2, ws0, ws1, ws2, bfv, bsv; };

__device__ __forceinline__ AggW load_aggw(const float* __restrict__ Wf_l,
                                          const float* __restrict__ bf_l,
                                          const float* __restrict__ Ws_l,
                                          const float* __restrict__ bs_l, int c0) {
    AggW a;
    a.wf0 = *(const float2*)&Wf_l[256 * H + c0];
    a.wf1 = *(const float2*)&Wf_l[257 * H + c0];
    a.wf2 = *(const float2*)&Wf_l[258 * H + c0];
    a.ws0 = *(const float2*)&Ws_l[256 * H + c0];
    a.ws1 = *(const float2*)&Ws_l[257 * H + c0];
    a.ws2 = *(const float2*)&Ws_l[258 * H + c0];
    a.bfv = *(const float2*)&bf_l[c0];
    a.bsv = *(const float2*)&bs_l[c0];
    return a;
}

// One 32-edge window, ring-16 q-prefetch (R5-proven shape), bias folded into
// the per-segment P load (same FP association -> bit-identical).
__device__ __forceinline__ void agg_window(int base,
                                           const int4* __restrict__ csr_fe,
                                           const int* __restrict__ csr_dst,
                                           const float* __restrict__ csr_inv,
                                           const unsigned* __restrict__ endmask,
                                           const AggW& aw,
                                           const uint_t* __restrict__ ppack,
                                           const uint_t* __restrict__ qpack,
                                           float* __restrict__ h, int lane) {
    int c0 = 2 * lane;
    int4 fe = csr_fe[base + (lane & (EPW - 1))];
    int  dd = csr_dst[base + (lane & (EPW - 1))];
    int  ivr = __float_as_int(csr_inv[base + (lane & (EPW - 1))]);
    unsigned mask = __builtin_amdgcn_readfirstlane(endmask[base >> 5]);

    uint2 q[QR];
#pragma unroll
    for (int i = 0; i < QR; ++i) {
        int s = __builtin_amdgcn_readlane(fe.w, i);
        q[i] = *(const uint2*)&qpack[(size_t)s * H + c0];
    }

    int dcur = __builtin_amdgcn_readlane(dd, 0);
    uint2 ppc = *(const uint2*)&ppack[(size_t)dcur * H + c0];
    float pf0 = __uint_as_float(ppc.x << 16) + aw.bfv.x;
    float ps0 = __uint_as_float(ppc.x & 0xFFFF0000u) + aw.bsv.x;
    float pf1 = __uint_as_float(ppc.y << 16) + aw.bfv.y;
    float ps1 = __uint_as_float(ppc.y & 0xFFFF0000u) + aw.bsv.y;
    unsigned m = mask;
    int e0 = m ? __builtin_ctz(m) : EPW;
    int dnext = 0;
    uint2 ppN = ppc;
    if (e0 + 1 < EPW) {
        dnext = __builtin_amdgcn_readlane(dd, e0 + 1);
        ppN = *(const uint2*)&ppack[(size_t)dnext * H + c0];
    }

    float acc0 = 0.f, acc1 = 0.f;

#pragma unroll
    for (int tb = 0; tb < EPW; tb += 8) {
#pragma unroll
        for (int i = 0; i < 8; ++i) {
            int t = tb + i;
            float ex = __int_as_float(__builtin_amdgcn_readlane(fe.x, t));
            float ey = __int_as_float(__builtin_amdgcn_readlane(fe.y, t));
            float ez = __int_as_float(__builtin_amdgcn_readlane(fe.z, t));
            uint2 qq = q[t & (QR - 1)];
            if (t + QR < EPW) {
                int s2 = __builtin_amdgcn_readlane(fe.w, t + QR);
                q[t & (QR - 1)] = *(const uint2*)&qpack[(size_t)s2 * H + c0];
            }
            float qf0 = __uint_as_float(qq.x << 16);
            float qs0 = __uint_as_float(qq.x & 0xFFFF0000u);
            float qf1 = __uint_as_float(qq.y << 16);
            float qs1 = __uint_as_float(qq.y & 0xFFFF0000u);
            float f0 = fmaf(ex, aw.wf0.x, fmaf(ey, aw.wf1.x, fmaf(ez, aw.wf2.x, pf0 + qf0)));
            float v0 = fmaf(ex, aw.ws0.x, fmaf(ey, aw.ws1.x, fmaf(ez, aw.ws2.x, ps0 + qs0)));
            float f1 = fmaf(ex, aw.wf0.y, fmaf(ey, aw.wf1.y, fmaf(ez, aw.wf2.y, pf1 + qf1)));
            float v1 = fmaf(ex, aw.ws0.y, fmaf(ey, aw.ws1.y, fmaf(ez, aw.ws2.y, ps1 + qs1)));
            float sig0 = __builtin_amdgcn_rcpf(1.0f + __expf(-f0));
            float sp0  = fmaxf(v0, 0.0f) + __logf(1.0f + __expf(-fabsf(v0)));
            float sig1 = __builtin_amdgcn_rcpf(1.0f + __expf(-f1));
            float sp1  = fmaxf(v1, 0.0f) + __logf(1.0f + __expf(-fabsf(v1)));
            acc0 = fmaf(sig0, sp0, acc0);
            acc1 = fmaf(sig1, sp1, acc1);
            if (mask & (1u << t)) {   // wave-uniform segment end (precomputed)
                float inv = __int_as_float(__builtin_amdgcn_readlane(ivr, t));
                atomicAdd(&h[(size_t)dcur * H + c0], acc0 * inv);
                atomicAdd(&h[(size_t)dcur * H + c0 + 1], acc1 * inv);
                acc0 = 0.f; acc1 = 0.f;
                dcur = dnext;
                pf0 = __uint_as_float(ppN.x << 16) + aw.bfv.x;
                ps0 = __uint_as_float(ppN.x & 0xFFFF0000u) + aw.bsv.x;
                pf1 = __uint_as_float(ppN.y << 16) + aw.bfv.y;
                ps1 = __uint_as_float(ppN.y & 0xFFFF0000u) + aw.bsv.y;
                m &= m - 1;
                int e1 = m ? __builtin_ctz(m) : EPW;
                if (e1 + 1 < EPW) {
                    dnext = __builtin_amdgcn_readlane(dd, e1 + 1);
                    ppN = *(const uint2*)&ppack[(size_t)dnext * H + c0];
                }
            }
        }
    }
    if (!(mask & (1u << (EPW - 1)))) {   // trailing partial segment
        float inv = __int_as_float(__builtin_amdgcn_readlane(ivr, EPW - 1));
        atomicAdd(&h[(size_t)dcur * H + c0], acc0 * inv);
        atomicAdd(&h[(size_t)dcur * H + c0 + 1], acc1 * inv);
    }
}

__device__ __forceinline__ void stats_part(const float* __restrict__ h,
                                           float* __restrict__ sum,
                                           float* __restrict__ sumsq,
                                           int j, int part, int nparts) {
    float s = 0.0f, ss = 0.0f;
    for (int n = part * 8; n + 7 < NN; n += nparts * 8) {
        float v[8];
#pragma unroll
        for (int i = 0; i < 8; ++i) v[i] = h[(size_t)(n + i) * H + j];
#pragma unroll
        for (int i = 0; i < 8; ++i) { s += v[i]; ss = fmaf(v[i], v[i], ss); }
    }
    atomicAdd(&sum[j], s);
    atomicAdd(&sumsq[j], ss);
}

// ================= cooperative mega-kernel v2 (LDS-free phases) =============
// 1024 blocks (4/CU co-resident; launcher verifies), 14 grid.syncs replace
// 14 dispatch boundaries. Phase shapes match the proven standalone kernels.
__global__ __launch_bounds__(256, 4) void mega_kernel(const int4* __restrict__ csr_fe,
                                                      const int* __restrict__ csr_dst,
                                                      const float* __restrict__ csr_inv,
                                                      const unsigned* __restrict__ endmask,
                                                      const float* __restrict__ Wf,
                                                      const float* __restrict__ bf,
                                                      const float* __restrict__ Ws,
                                                      const float* __restrict__ bs,
                                                      const ushort_t* __restrict__ Wt,
                                                      float* __restrict__ hA,
                                                      float* __restrict__ hB,
                                                      uint_t* __restrict__ ppack,
                                                      uint_t* __restrict__ qpack,
                                                      float* __restrict__ sum,
                                                      float* __restrict__ sumsq,
                                                      const float* __restrict__ gamma,
                                                      const float* __restrict__ beta) {
    cg::grid_group grid = cg::this_grid();
    __shared__ float bnsc[H];
    __shared__ float bnsh[H];
    int tid = threadIdx.x;
    int lane = tid & 63;
    int wv = tid >> 6;

    for (int l = 0; l < NL; ++l) {
        const float* hsrc = (l == 0) ? hA : ((l & 1) ? hA : hB);
        float* hTgt = (l == 0) ? hA : ((l & 1) ? hB : hA);
        const ushort_t* Wt_l = Wt + (size_t)l * 512 * H;
        int applyBN = (l > 0);

        // ---- phase 1: node GEMM (626 items, ~1 per block) ----
        if (applyBN) {
            if (tid < H) {
                float mu  = sum[tid] * (1.0f / NN);
                float var = sumsq[tid] * (1.0f / NN) - mu * mu;
                float sc  = gamma[(size_t)(l - 1) * H + tid] * rsqrtf(var + BN_EPSF);
                bnsc[tid] = sc;
                bnsh[tid] = beta[(size_t)(l - 1) * H + tid] - mu * sc;
            }
            __syncthreads();
        }
        for (int item = blockIdx.x; item < 2 * MBLK; item += gridDim.x) {
            int pair = item >= MBLK;
            gemm_item(pair ? item - MBLK : item, pair, hsrc, hTgt, Wt_l,
                      bnsc, bnsh, applyBN, ppack, qpack, tid);
        }
        grid.sync();

        // ---- phase 2: edge aggregation (5000 windows over 4096 waves) ----
        if (blockIdx.x == 0 && tid < H) { sum[tid] = 0.0f; sumsq[tid] = 0.0f; }
        {
            AggW aw = load_aggw(Wf + (size_t)l * ZDH, bf + (size_t)l * H,
                                Ws + (size_t)l * ZDH, bs + (size_t)l * H, 2 * lane);
            for (int w = blockIdx.x * 4 + wv; w < NWIN; w += gridDim.x * 4)
                agg_window(w * EPW, csr_fe, csr_dst, csr_inv, endmask, aw,
                           ppack, qpack, hTgt, lane);
        }
        grid.sync();

        // ---- phase 3: BN stats (same 512-part shape as standalone) ----
        if (blockIdx.x < 256)
            stats_part(hTgt, sum, sumsq, tid & 127, blockIdx.x * 2 + (tid >> 7), 512);
        if (l < NL - 1) grid.sync();   // final barrier = kernel end
    }
}

// ================= standalone fallback kernels (R5/R6-proven) ===============
__global__ __launch_bounds__(256, 4) void node_gemm_mfma(const float* __restrict__ hsrc,
                                                         float* __restrict__ hbn,
                                                         const ushort_t* __restrict__ Wt_l,
                                                         const float* __restrict__ sum,
                                                         const float* __restrict__ sumsq,
                                                         const float* __restrict__ gamma_l,
                                                         const float* __restrict__ beta_l,
                                                         int applyBN,
                                                         uint_t* __restrict__ ppack,
                                                         uint_t* __restrict__ qpack) {
    __shared__ float bnsc[H];
    __shared__ float bnsh[H];
    int tid = threadIdx.x;
    if (applyBN) {
        if (tid < H) {
            float mu  = sum[tid] * (1.0f / NN);
            float var = sumsq[tid] * (1.0f / NN) - mu * mu;
            float sc  = gamma_l[tid] * rsqrtf(var + BN_EPSF);
            bnsc[tid] = sc;
            bnsh[tid] = beta_l[tid] - mu * sc;
        }
        __syncthreads();
    }
    gemm_item(blockIdx.x, blockIdx.y, hsrc, hbn, Wt_l, bnsc, bnsh,
              applyBN, ppack, qpack, tid);
}

__global__ __launch_bounds__(256) void agg_edge_kernel(const int4* __restrict__ csr_fe,
                                                       const int* __restrict__ csr_dst,
                                                       const float* __restrict__ csr_inv,
                                                       const unsigned* __restrict__ endmask,
                                                       const float* __restrict__ Wf_l,
                                                       const float* __restrict__ bf_l,
                                                       const float* __restrict__ Ws_l,
                                                       const float* __restrict__ bs_l,
                                                       const uint_t* __restrict__ ppack,
                                                       const uint_t* __restrict__ qpack,
                                                       float* __restrict__ h,
                                                       float* __restrict__ sum,
                                                       float* __restrict__ sumsq) {
    int tid = threadIdx.x;
    if (blockIdx.x == 0 && tid < H) { sum[tid] = 0.0f; sumsq[tid] = 0.0f; }
    int lane = tid & 63;
    int wv = tid >> 6;
    AggW aw = load_aggw(Wf_l, bf_l, Ws_l, bs_l, 2 * lane);
    agg_window((blockIdx.x * 4 + wv) * EPW, csr_fe, csr_dst, csr_inv, endmask, aw,
               ppack, qpack, h, lane);
}

__global__ __launch_bounds__(H) void stats_kernel(const float* __restrict__ h,
                                                  float* __restrict__ sum,
                                                  float* __restrict__ sumsq) {
    stats_part(h, sum, sumsq, threadIdx.x, blockIdx.x, gridDim.x);
}

// Fused global-mean-pool (atomic-free via gstart) + BN/ReLU + 3-layer MLP.
__global__ __launch_bounds__(H) void pool_mlp_kernel(const float* __restrict__ h,
                                                     const int* __restrict__ gstart,
                                                     const float* __restrict__ sum,
                                                     const float* __restrict__ sumsq,
                                                     const float* __restrict__ gamma,
                                                     const float* __restrict__ beta,
                                                     const float* __restrict__ W1,
                                                     const float* __restrict__ b1,
                                                     const float* __restrict__ W2,
                                                     const float* __restrict__ b2,
                                                     const float* __restrict__ W3,
                                                     const float* __restrict__ b3,
                                                     float* __restrict__ out) {
    int j = threadIdx.x;
    float mu  = sum[j] * (1.0f / NN);
    float var = sumsq[j] * (1.0f / NN) - mu * mu;
    float sc  = gamma[j] * rsqrtf(var + BN_EPSF);
    float sh  = beta[j] - mu * sc;

    __shared__ float s1[GP][H];
    __shared__ float s2[GP][H];

#pragma unroll
    for (int gi = 0; gi < GP; ++gi) {
        int g0 = blockIdx.x * GP + gi;
        int a = gstart[g0], e = gstart[g0 + 1];
        float p0 = 0.f, p1 = 0.f, p2 = 0.f, p3 = 0.f;
        int n = a;
        for (; n + 3 < e; n += 4) {
            float v0 = fmaf(h[(size_t)(n + 0) * H + j], sc, sh);
            float v1 = fmaf(h[(size_t)(n + 1) * H + j], sc, sh);
            float v2 = fmaf(h[(size_t)(n + 2) * H + j], sc, sh);
            float v3 = fmaf(h[(size_t)(n + 3) * H + j], sc, sh);
            p0 += fmaxf(v0, 0.f); p1 += fmaxf(v1, 0.f);
            p2 += fmaxf(v2, 0.f); p3 += fmaxf(v3, 0.f);
        }
        for (; n < e; ++n) {
            float v = fmaf(h[(size_t)n * H + j], sc, sh);
            p0 += fmaxf(v, 0.f);
        }
        float cf = (float)(e - a);
        if (cf < 1.f) cf = 1.f;
        s1[gi][j] = ((p0 + p1) + (p2 + p3)) / cf;
    }
    __syncthreads();

    float a1[GP];
#pragma unroll
    for (int gi = 0; gi < GP; ++gi) a1[gi] = b1[j];
    for (int k = 0; k < H; ++k) {
        float w = W1[k * H + j];
#pragma unroll
        for (int gi = 0; gi < GP; ++gi) a1[gi] = fmaf(s1[gi][k], w, a1[gi]);
    }
#pragma unroll
    for (int gi = 0; gi < GP; ++gi) s2[gi][j] = fmaxf(a1[gi], 0.f);
    __syncthreads();

#pragma unroll
    for (int gi = 0; gi < GP; ++gi) a1[gi] = b2[j];
    for (int k = 0; k < H; ++k) {
        float w = W2[k * H + j];
#pragma unroll
        for (int gi = 0; gi < GP; ++gi) a1[gi] = fmaf(s2[gi][k], w, a1[gi]);
    }

    float w3 = W3[j];
    __shared__ float wred[2][GP];
#pragma unroll
    for (int gi = 0; gi < GP; ++gi) {
        float p = fmaxf(a1[gi], 0.f) * w3;
        for (int off2 = 32; off2 > 0; off2 >>= 1) p += __shfl_down(p, off2, 64);
        if ((j & 63) == 0) wred[j >> 6][gi] = p;
    }
    __syncthreads();
    if (j < GP) out[blockIdx.x * GP + j] = wred[0][j] + wred[1][j] + b3[0];
}

extern "C" void kernel_launch(void* const* d_in, const int* in_sizes, int n_in,
                              void* d_out, int out_size, void* d_ws, size_t ws_size,
                              hipStream_t stream) {
    const float* x     = (const float*)d_in[0];
    const int*   ei    = (const int*)d_in[1];
    const int*   srcp  = ei;        // edge_index[0] = source (x_j)
    const int*   dstp  = ei + NE;   // edge_index[1] = target (aggregation index)
    const int*   batch = (const int*)d_in[2];
    const float* ea    = (const float*)d_in[3];
    const float* Win   = (const float*)d_in[4];
    const float* bin   = (const float*)d_in[5];
    const float* Wf    = (const float*)d_in[6];
    const float* bf    = (const float*)d_in[7];
    const float* Ws    = (const float*)d_in[8];
    const float* bs    = (const float*)d_in[9];
    const float* gamma = (const float*)d_in[10];
    const float* beta  = (const float*)d_in[11];
    const float* W1    = (const float*)d_in[12];
    const float* b1    = (const float*)d_in[13];
    const float* W2    = (const float*)d_in[14];
    const float* b2    = (const float*)d_in[15];
    const float* W3    = (const float*)d_in[16];
    const float* b3    = (const float*)d_in[17];
    float* out = (float*)d_out;

    const size_t NH = (size_t)NN * H;
    float* wsp = (float*)d_ws;
    size_t off = 0;
    float* hA     = wsp + off; off += NH;
    float* hB     = wsp + off; off += NH;
    uint_t* ppack = (uint_t*)(wsp + off); off += NH;  // packed bf16 (Pf,Ps)
    uint_t* qpack = (uint_t*)(wsp + off); off += NH;  // packed bf16 (Qf,Qs)
    float* invdeg = wsp + off; off += NN;
    float* sum    = wsp + off; off += H;
    float* sumsq  = wsp + off; off += H;
    int* gstart   = (int*)(wsp + off); off += NG + 1;
    off = (off + 3) & ~(size_t)3;
    float4* csr_ea4 = (float4*)(wsp + off); off += (size_t)NE * 4;
    float* csr_inv = wsp + off; off += NE;
    int* degi      = (int*)(wsp + off); off += NN;
    int* counter   = (int*)(wsp + off); off += 1;
    unsigned* endmask = (unsigned*)(wsp + off); off += NE / 32;
    int* cursor    = (int*)(wsp + off); off += NN;
    int* csr_dst   = (int*)(wsp + off); off += NE;
    off = (off + 3) & ~(size_t)3;
    ushort_t* Wt = (ushort_t*)(wsp + off); off += (size_t)NL * 512 * H / 2;

    // ---- CSR + weight prep ----
    hipMemsetAsync(degi, 0, (NN + 1 + NE / 32) * sizeof(int), stream);
    prep_fused<<<PREP_GRID, 256, 0, stream>>>(dstp, degi, Wf, Ws, Wt,
                                              x, Win, bin, hA, batch, gstart);
    reserve_kernel<<<(NN + 255) / 256, 256, 0, stream>>>(degi, cursor, invdeg, counter,
                                                         endmask);
    scatter_kernel<<<(NE + 255) / 256, 256, 0, stream>>>(srcp, dstp, ea, invdeg, cursor,
                                                         csr_ea4, csr_dst, csr_inv);

    // ---- 5-layer loop: cooperative mega (requires 4 blocks/CU) ----
    static int megaOK = -1;
    if (megaOK < 0) {
        int nb = 0;
        hipError_t oe = hipOccupancyMaxActiveBlocksPerMultiprocessor(&nb, mega_kernel, 256, 0);
        megaOK = (oe == hipSuccess && nb >= 4) ? 1 : 0;
    }
    bool megaDone = false;
    if (megaOK) {
        const int4* csr_fe_p = (const int4*)csr_ea4;
        const int* csr_dst_p = csr_dst;
        const float* csr_inv_p = csr_inv;
        const unsigned* endmask_p = endmask;
        const float* Wf_p = Wf;  const float* bf_p = bf;
        const float* Ws_p = Ws;  const float* bs_p = bs;
        const ushort_t* Wt_p = Wt;
        float* hA_p = hA;  float* hB_p = hB;
        uint_t* pp_p = ppack;  uint_t* qp_p = qpack;
        float* sum_p = sum;  float* sumsq_p = sumsq;
        const float* gamma_p = gamma;  const float* beta_p = beta;
        void* margs[] = {&csr_fe_p, &csr_dst_p, &csr_inv_p, &endmask_p,
                         &Wf_p, &bf_p, &Ws_p, &bs_p, &Wt_p,
                         &hA_p, &hB_p, &pp_p, &qp_p, &sum_p, &sumsq_p,
                         &gamma_p, &beta_p};
        hipError_t merr = hipLaunchCooperativeKernel(mega_kernel, dim3(MEGA_BLOCKS),
                                                     dim3(256), margs, 0, stream);
        if (merr == hipSuccess) megaDone = true;
        else (void)hipGetLastError();
    }
    float* hRead = hA;   // NL=5: layer 4 (even) target = hA
    if (!megaDone) {
        // fallback: proven per-layer path (R5, 461 us)
        hRead = hA;
        for (int l = 0; l < NL; ++l) {
            float* hTgt = (l == 0) ? hA : ((l & 1) ? hB : hA);
            node_gemm_mfma<<<dim3(MBLK, 2), 256, 0, stream>>>(
                hRead, hTgt, Wt + (size_t)l * 512 * H, sum, sumsq,
                gamma + (size_t)(l ? l - 1 : 0) * H,
                beta  + (size_t)(l ? l - 1 : 0) * H,
                l > 0, ppack, qpack);
            agg_edge_kernel<<<NWIN / 4, 256, 0, stream>>>((const int4*)csr_ea4, csr_dst,
                                                          csr_inv, endmask,
                                                          Wf + (size_t)l * ZDH, bf + (size_t)l * H,
                                                          Ws + (size_t)l * ZDH, bs + (size_t)l * H,
                                                          ppack, qpack, hTgt, sum, sumsq);
            stats_kernel<<<512, H, 0, stream>>>(hTgt, sum, sumsq);
            hRead = hTgt;
        }
    }

    pool_mlp_kernel<<<NG / GP, H, 0, stream>>>(hRead, gstart, sum, sumsq,
                                               gamma + (size_t)(NL - 1) * H,
                                               beta + (size_t)(NL - 1) * H,
                                               W1, b1, W2, b2, W3, b3, out);
}